// Round 1
// baseline (325.879 us; speedup 1.0000x reference)
//
#include <hip/hip_runtime.h>
#include <stdint.h>

// ---------------------------------------------------------------------------
// Kernel 1: s[row] = dot(x[row, :], w) + b   (row = f*T + t), f64 accumulate.
// One wave (64 lanes) per row; float4 loads, lane-strided; shfl reduce.
// ---------------------------------------------------------------------------
__global__ void score_kernel(const float* __restrict__ x,
                             const float* __restrict__ w,
                             const float* __restrict__ b,
                             double* __restrict__ s,
                             int nrows, int D) {
    int gtid = blockIdx.x * blockDim.x + threadIdx.x;
    int row  = gtid >> 6;
    int lane = threadIdx.x & 63;
    if (row >= nrows) return;

    const float4* xr = (const float4*)(x + (size_t)row * D);
    const float4* wr = (const float4*)w;
    int n4 = D >> 2;

    double acc = 0.0;
    for (int p = lane; p < n4; p += 64) {
        float4 a = xr[p];
        float4 c = wr[p];
        acc += (double)a.x * (double)c.x + (double)a.y * (double)c.y +
               (double)a.z * (double)c.z + (double)a.w * (double)c.w;
    }
#pragma unroll
    for (int off = 32; off > 0; off >>= 1) acc += __shfl_down(acc, off);
    if (lane == 0) s[row] = acc + (double)b[0];
}

// ---------------------------------------------------------------------------
// Kernel 2: per frame f (one block, blockDim == T):
//   logits[t] = bias[t] + sum_tp s[f,tp] * W[tp,t]           (f64 accum)
//   top-K by (logit desc, token asc)  == argsort(-softmax) stable top-K
//   output the K winning token indices sorted ascending.
// Assumes T <= 1024, K <= 256.
// ---------------------------------------------------------------------------
__global__ void topk_kernel(const double* __restrict__ s,
                            const float* __restrict__ W,
                            const float* __restrict__ bias,
                            int* __restrict__ idx_out,
                            int T, int K) {
    __shared__ double   s_sh[1024];
    __shared__ double   val[1024];
    __shared__ int      tok[1024];
    __shared__ unsigned ids[256];

    const int f   = blockIdx.x;
    const int tid = threadIdx.x;

    s_sh[tid] = s[(size_t)f * T + tid];
    __syncthreads();

    // GEMV column tid: coalesced W reads across threads (W is L2-resident).
    double acc = (double)bias[tid];
    const float* Wc = W + tid;
    for (int tp = 0; tp < T; ++tp)
        acc += s_sh[tp] * (double)Wc[(size_t)tp * T];

    val[tid] = acc;
    tok[tid] = tid;
    for (int i = T + tid; i < 1024; i += T) { val[i] = -1e300; tok[i] = 0x7FFFFFFF; }

    // Bitonic sort, 1024 slots, order: value desc, token asc on ties.
    for (int k = 2; k <= 1024; k <<= 1) {
        for (int j = k >> 1; j > 0; j >>= 1) {
            __syncthreads();
            for (int i = tid; i < 1024; i += T) {
                int ixj = i ^ j;
                if (ixj > i) {
                    double va = val[i], vb = val[ixj];
                    int    ta = tok[i], tb = tok[ixj];
                    bool a_before_b = (va > vb) || (va == vb && ta < tb);
                    bool desc = ((i & k) == 0);
                    if (a_before_b != desc) {
                        val[i] = vb; val[ixj] = va;
                        tok[i] = tb; tok[ixj] = ta;
                    }
                }
            }
        }
    }
    __syncthreads();

    // Take first K tokens, sort them ascending (256-slot bitonic, pad 0xFFFFFFFF).
    if (tid < 256) ids[tid] = (tid < K) ? (unsigned)tok[tid] : 0xFFFFFFFFu;
    for (int k = 2; k <= 256; k <<= 1) {
        for (int j = k >> 1; j > 0; j >>= 1) {
            __syncthreads();
            if (tid < 256) {
                int i = tid, ixj = i ^ j;
                if (ixj > i) {
                    unsigned a = ids[i], b2 = ids[ixj];
                    bool asc = ((i & k) == 0);
                    if ((a > b2) == asc) { ids[i] = b2; ids[ixj] = a; }
                }
            }
        }
    }
    __syncthreads();
    if (tid < K) idx_out[(size_t)f * K + tid] = (int)ids[tid];
}

// ---------------------------------------------------------------------------
// Kernel 3: out[f, k, :] = x[f, idx[f,k], :]. One wave per output row, float4.
// ---------------------------------------------------------------------------
__global__ void gather_kernel(const float* __restrict__ x,
                              const int* __restrict__ idx,
                              float* __restrict__ out,
                              int nrows, int T, int K, int D) {
    int gtid = blockIdx.x * blockDim.x + threadIdx.x;
    int row  = gtid >> 6;
    int lane = threadIdx.x & 63;
    if (row >= nrows) return;

    int f = row / K;
    int t = idx[row];

    const float4* src = (const float4*)(x + ((size_t)f * T + (size_t)t) * D);
    float4*       dst = (float4*)(out + (size_t)row * D);
    int n4 = D >> 2;
    for (int p = lane; p < n4; p += 64) dst[p] = src[p];
}

// ---------------------------------------------------------------------------
extern "C" void kernel_launch(void* const* d_in, const int* in_sizes, int n_in,
                              void* d_out, int out_size, void* d_ws, size_t ws_size,
                              hipStream_t stream) {
    const float* x     = (const float*)d_in[0];
    const float* pre_w = (const float*)d_in[1];
    const float* pre_b = (const float*)d_in[2];
    const float* W     = (const float*)d_in[3];
    const float* bias  = (const float*)d_in[4];
    // d_in[5] = n_frames, d_in[6] = out_token_num: only affect the reshape,
    // which is a no-op on the flat [F, K, D] layout; K derived from out_size.

    const int D = in_sizes[1];          // pre_w is [1, D]
    const int T = in_sizes[4];          // trans_bias is [T]
    const int F = in_sizes[0] / (T * D);
    const int K = out_size / (F * D);

    double* s_buf = (double*)d_ws;
    int*    idx   = (int*)((char*)d_ws + (size_t)F * T * sizeof(double));

    int nrows1  = F * T;
    int blocks1 = (nrows1 * 64 + 255) / 256;
    score_kernel<<<blocks1, 256, 0, stream>>>(x, pre_w, pre_b, s_buf, nrows1, D);

    topk_kernel<<<F, T, 0, stream>>>(s_buf, W, bias, idx, T, K);

    int nrows3  = F * K;
    int blocks3 = (nrows3 * 64 + 255) / 256;
    gather_kernel<<<blocks3, 256, 0, stream>>>(x, idx, (float*)d_out, nrows3, T, K, D);
}

// Round 2
// 310.377 us; speedup vs baseline: 1.0499x; 1.0499x over previous
//
#include <hip/hip_runtime.h>
#include <stdint.h>

typedef float f4 __attribute__((ext_vector_type(4)));

// One block per frame, 1024 threads (16 waves).
// Phase 1: s[t] = <x[f,t,:], pre_w> + pre_b      (wave per token row, f64 accum)
// Phase 2: logits[t] = bias[t] + sum_tp s[tp]*W[tp,t]   (f64, unrolled x4)
// Phase 3: bitonic sort 1024 slots by (logit desc, token asc)
//          == stable argsort(-softmax) top-K (softmax is monotonic -> skipped)
// Phase 3b: bitmask+popcount compaction -> selected tokens in ascending order
// Phase 4: gather the K selected rows, nontemporal stores
__global__ __launch_bounds__(1024)
void fused_select_kernel(const float* __restrict__ x,
                         const float* __restrict__ pre_w,
                         const float* __restrict__ pre_b,
                         const float* __restrict__ W,
                         const float* __restrict__ bias,
                         float* __restrict__ out,
                         int T, int D, int K) {
    __shared__ double   s_sh[1024];
    __shared__ double   val[1024];
    __shared__ int      tok[1024];
    __shared__ unsigned flags[32];
    __shared__ int      sel[576];

    const int f    = blockIdx.x;
    const int tid  = threadIdx.x;
    const int wave = tid >> 6;
    const int lane = tid & 63;
    const int nw   = blockDim.x >> 6;
    const int n4   = D >> 2;

    // ---------------- Phase 1: per-token scores ----------------
    const f4* wv = (const f4*)pre_w;
    for (int t = wave; t < T; t += nw) {
        const f4* xr = (const f4*)(x + ((size_t)f * T + t) * D);
        double acc = 0.0;
        for (int p = lane; p < n4; p += 64) {
            f4 a = xr[p], c = wv[p];
            acc += (double)a.x * (double)c.x + (double)a.y * (double)c.y
                 + (double)a.z * (double)c.z + (double)a.w * (double)c.w;
        }
#pragma unroll
        for (int off = 32; off > 0; off >>= 1) acc += __shfl_down(acc, off);
        if (lane == 0) s_sh[t] = acc + (double)pre_b[0];
    }
    __syncthreads();

    // ---------------- Phase 2: GEMV logits ----------------
    if (tid < T) {
        const float* Wc = W + tid;
        double a0 = 0, a1 = 0, a2 = 0, a3 = 0;
        int tp = 0;
        for (; tp + 4 <= T; tp += 4) {
            a0 += s_sh[tp + 0] * (double)Wc[(size_t)(tp + 0) * T];
            a1 += s_sh[tp + 1] * (double)Wc[(size_t)(tp + 1) * T];
            a2 += s_sh[tp + 2] * (double)Wc[(size_t)(tp + 2) * T];
            a3 += s_sh[tp + 3] * (double)Wc[(size_t)(tp + 3) * T];
        }
        for (; tp < T; ++tp) a0 += s_sh[tp] * (double)Wc[(size_t)tp * T];
        val[tid] = ((a0 + a1) + (a2 + a3)) + (double)bias[tid];
        tok[tid] = tid;
    } else {
        val[tid] = -1.0e300;
        tok[tid] = 0x7FFFFFFF;
    }

    // ---------------- Phase 3: bitonic sort (1024, one elem/thread) ----------------
    for (int k = 2; k <= 1024; k <<= 1) {
        for (int j = k >> 1; j > 0; j >>= 1) {
            __syncthreads();
            int i = tid, ixj = i ^ j;
            if (ixj > i) {
                double va = val[i], vb = val[ixj];
                int    ta = tok[i], tb = tok[ixj];
                bool a_first = (va > vb) || (va == vb && ta < tb);
                bool desc    = ((i & k) == 0);
                if (a_first != desc) {
                    val[i] = vb; val[ixj] = va;
                    tok[i] = tb; tok[ixj] = ta;
                }
            }
        }
    }
    __syncthreads();

    // ---------------- Phase 3b: ascending compaction of top-K tokens ----------------
    if (tid < 32) flags[tid] = 0u;
    __syncthreads();
    if (tid < K) atomicOr(&flags[tok[tid] >> 5], 1u << (tok[tid] & 31));
    __syncthreads();
    if (tid < K) {
        int t = tok[tid];
        int w = t >> 5;
        int pos = __popc(flags[w] & ((1u << (t & 31)) - 1u));
        for (int u = 0; u < w; ++u) pos += __popc(flags[u]);
        sel[pos] = t;
    }
    __syncthreads();

    // ---------------- Phase 4: gather selected rows ----------------
    for (int k2 = wave; k2 < K; k2 += nw) {
        int t = sel[k2];
        const f4* src = (const f4*)(x + ((size_t)f * T + t) * D);
        f4*       dst = (f4*)(out + ((size_t)f * K + k2) * D);
        for (int p = lane; p < n4; p += 64)
            __builtin_nontemporal_store(src[p], &dst[p]);
    }
}

extern "C" void kernel_launch(void* const* d_in, const int* in_sizes, int n_in,
                              void* d_out, int out_size, void* d_ws, size_t ws_size,
                              hipStream_t stream) {
    const float* x     = (const float*)d_in[0];
    const float* pre_w = (const float*)d_in[1];
    const float* pre_b = (const float*)d_in[2];
    const float* W     = (const float*)d_in[3];
    const float* bias  = (const float*)d_in[4];

    const int D = in_sizes[1];          // pre_w is [1, D]
    const int T = in_sizes[4];          // trans_bias is [T]
    const int F = in_sizes[0] / (T * D);
    const int K = out_size / (F * D);

    fused_select_kernel<<<F, 1024, 0, stream>>>(x, pre_w, pre_b, W, bias,
                                                (float*)d_out, T, D, K);
}